// Round 5
// baseline (263.647 us; speedup 1.0000x reference)
//
#include <hip/hip_runtime.h>

// image: [8, 512, 512, 16] f32, flow: [8, 512, 512, 2] f32 -> out: [8, 512, 512, 16] f32
constexpr int B = 8;
constexpr int H = 512;
constexpr int W = 512;
constexpr int C = 16;
constexpr int NPIX = B * H * W;              // 2,097,152 pixels
constexpr int ITERS = 4;                     // pixel-groups per thread (ILP batching)
constexpr int TOTAL_ELEMS = NPIX * 4;        // 4 float4-groups per pixel
constexpr int NTHREADS = TOTAL_ELEMS / ITERS;
constexpr int BLOCK = 256;
constexpr int NBLOCKS = NTHREADS / BLOCK;    // 8192, divisible by 8 XCDs
constexpr int NXCD = 8;

typedef float f4 __attribute__((ext_vector_type(4)));

__device__ __forceinline__ f4 lerp4(f4 a, f4 b, float t) {
    return a + t * (b - a);
}

__global__ __launch_bounds__(256) void warp_bilinear_kernel(
    const float* __restrict__ image,
    const float* __restrict__ flow,
    float* __restrict__ out) {

    // XCD-contiguous swizzle (8 XCDs, round-robin hardware dispatch).
    int bid = blockIdx.x;
    int swz = (bid & (NXCD - 1)) * (NBLOCKS / NXCD) + (bid >> 3);
    int t = swz * BLOCK + threadIdx.x;
    int g = t & 3;  // channel group (constant across iters since NTHREADS % 4 == 0)

    // Phase A: all flow loads (independent — 4 outstanding).
    int pixs[ITERS];
    float2 fl[ITERS];
#pragma unroll
    for (int i = 0; i < ITERS; ++i) {
        int e = t + i * NTHREADS;
        pixs[i] = e >> 2;
        fl[i] = *reinterpret_cast<const float2*>(flow + (size_t)pixs[i] * 2);
    }

    // Phase B: all gather loads (16 outstanding f4 loads).
    f4 tl[ITERS], tr[ITERS], bl[ITERS], br[ITERS];
    float ax[ITERS], ay[ITERS];
#pragma unroll
    for (int i = 0; i < ITERS; ++i) {
        int p = pixs[i];
        int x = p & (W - 1);
        int y = (p >> 9) & (H - 1);
        int b = p >> 18;
        float qy = (float)y - fl[i].x;
        float qx = (float)x - fl[i].y;
        float fy = fminf(fmaxf(floorf(qy), 0.0f), (float)(H - 2));
        float fx = fminf(fmaxf(floorf(qx), 0.0f), (float)(W - 2));
        ay[i] = fminf(fmaxf(qy - fy, 0.0f), 1.0f);
        ax[i] = fminf(fmaxf(qx - fx, 0.0f), 1.0f);
        int iy = (int)fy;
        int ix = (int)fx;
        const f4* base =
            reinterpret_cast<const f4*>(image + ((((size_t)b * H + iy) * W) + ix) * C);
        tl[i] = base[g];
        tr[i] = base[4 + g];
        bl[i] = base[(W * C / 4) + g];
        br[i] = base[(W * C / 4) + 4 + g];
    }

    // Phase C: lerp + non-temporal stores (write-once output, keep out of L3).
#pragma unroll
    for (int i = 0; i < ITERS; ++i) {
        f4 top = lerp4(tl[i], tr[i], ax[i]);
        f4 bot = lerp4(bl[i], br[i], ax[i]);
        f4 res = lerp4(top, bot, ay[i]);
        f4* o = reinterpret_cast<f4*>(out + (size_t)pixs[i] * C) + g;
        __builtin_nontemporal_store(res, o);
    }
}

extern "C" void kernel_launch(void* const* d_in, const int* in_sizes, int n_in,
                              void* d_out, int out_size, void* d_ws, size_t ws_size,
                              hipStream_t stream) {
    const float* image = (const float*)d_in[0];
    const float* flow  = (const float*)d_in[1];
    float* out = (float*)d_out;

    warp_bilinear_kernel<<<NBLOCKS, BLOCK, 0, stream>>>(image, flow, out);
}

// Round 6
// 261.956 us; speedup vs baseline: 1.0065x; 1.0065x over previous
//
#include <hip/hip_runtime.h>

// image: [8, 512, 512, 16] f32, flow: [8, 512, 512, 2] f32 -> out: [8, 512, 512, 16] f32
constexpr int B = 8;
constexpr int H = 512;
constexpr int W = 512;
constexpr int C = 16;
constexpr int NPIX = B * H * W;              // 2,097,152 pixels
constexpr int ITERS = 4;                     // pixel-groups per thread (ILP batching)
constexpr int TOTAL_ELEMS = NPIX * 4;        // 4 float4-groups per pixel
constexpr int NTHREADS = TOTAL_ELEMS / ITERS;
constexpr int BLOCK = 256;
constexpr int NBLOCKS = NTHREADS / BLOCK;    // 8192, divisible by 8 XCDs
constexpr int NXCD = 8;

typedef float f4 __attribute__((ext_vector_type(4)));

__device__ __forceinline__ f4 lerp4(f4 a, f4 b, float t) {
    return a + t * (b - a);
}

__global__ __launch_bounds__(256) void warp_bilinear_kernel(
    const float* __restrict__ image,
    const float* __restrict__ flow,
    float* __restrict__ out) {

    // XCD-contiguous swizzle (8 XCDs, round-robin hardware dispatch).
    int bid = blockIdx.x;
    int swz = (bid & (NXCD - 1)) * (NBLOCKS / NXCD) + (bid >> 3);
    int t = swz * BLOCK + threadIdx.x;
    int g = t & 3;  // channel group (constant across iters since NTHREADS % 4 == 0)

    // ---- Phase A: all flow loads issue back-to-back (4 outstanding). ----
    int pixs[ITERS];
    float2 fl[ITERS];
#pragma unroll
    for (int i = 0; i < ITERS; ++i) {
        int e = t + i * NTHREADS;
        pixs[i] = e >> 2;
        fl[i] = *reinterpret_cast<const float2*>(flow + (size_t)pixs[i] * 2);
    }
    // Pin: no gather may be hoisted above, no flow load may sink below.
    // (In-order vmcnt means a flow load issued after gathers[i-1] would force
    //  waiting on those gathers — this barrier keeps one wait per phase.)
    __builtin_amdgcn_sched_barrier(0);

    // ---- Phase B: all 16 gather loads issue back-to-back. ----
    f4 tl[ITERS], tr[ITERS], bl[ITERS], br[ITERS];
    float ax[ITERS], ay[ITERS];
#pragma unroll
    for (int i = 0; i < ITERS; ++i) {
        int p = pixs[i];
        int x = p & (W - 1);
        int y = (p >> 9) & (H - 1);
        int b = p >> 18;
        float qy = (float)y - fl[i].x;
        float qx = (float)x - fl[i].y;
        float fy = fminf(fmaxf(floorf(qy), 0.0f), (float)(H - 2));
        float fx = fminf(fmaxf(floorf(qx), 0.0f), (float)(W - 2));
        ay[i] = fminf(fmaxf(qy - fy, 0.0f), 1.0f);
        ax[i] = fminf(fmaxf(qx - fx, 0.0f), 1.0f);
        int iy = (int)fy;
        int ix = (int)fx;
        const f4* base =
            reinterpret_cast<const f4*>(image + ((((size_t)b * H + iy) * W) + ix) * C);
        tl[i] = base[g];
        tr[i] = base[4 + g];
        bl[i] = base[(W * C / 4) + g];
        br[i] = base[(W * C / 4) + 4 + g];
    }
    // Pin: keep all 16 gathers in flight before any lerp consumes them.
    __builtin_amdgcn_sched_barrier(0);

    // ---- Phase C: lerp + non-temporal stores (write-once output). ----
#pragma unroll
    for (int i = 0; i < ITERS; ++i) {
        f4 top = lerp4(tl[i], tr[i], ax[i]);
        f4 bot = lerp4(bl[i], br[i], ax[i]);
        f4 res = lerp4(top, bot, ay[i]);
        f4* o = reinterpret_cast<f4*>(out + (size_t)pixs[i] * C) + g;
        __builtin_nontemporal_store(res, o);
    }
}

extern "C" void kernel_launch(void* const* d_in, const int* in_sizes, int n_in,
                              void* d_out, int out_size, void* d_ws, size_t ws_size,
                              hipStream_t stream) {
    const float* image = (const float*)d_in[0];
    const float* flow  = (const float*)d_in[1];
    float* out = (float*)d_out;

    warp_bilinear_kernel<<<NBLOCKS, BLOCK, 0, stream>>>(image, flow, out);
}

// Round 7
// 250.931 us; speedup vs baseline: 1.0507x; 1.0439x over previous
//
#include <hip/hip_runtime.h>

// image: [8, 512, 512, 16] f32, flow: [8, 512, 512, 2] f32 -> out: [8, 512, 512, 16] f32
constexpr int B = 8;
constexpr int H = 512;
constexpr int W = 512;
constexpr int C = 16;
constexpr int NPIX = B * H * W;            // 2,097,152 pixels
constexpr int NTHREADS = NPIX * 4;         // 4 threads per pixel (one float4 group each)
constexpr int BLOCK = 256;
constexpr int NBLOCKS = NTHREADS / BLOCK;  // 32768, divisible by 8 XCDs
constexpr int NXCD = 8;

typedef float f4 __attribute__((ext_vector_type(4)));

__device__ __forceinline__ f4 lerp4(f4 a, f4 b, float t) {
    return a + t * (b - a);
}

__global__ __launch_bounds__(256) void warp_bilinear_kernel(
    const float* __restrict__ image,
    const float* __restrict__ flow,
    float* __restrict__ out) {

    // XCD-contiguous swizzle: each XCD owns one contiguous batch image,
    // keeping row y / y+1 gather reuse inside one L2.
    int bid = blockIdx.x;
    int swz = (bid & (NXCD - 1)) * (NBLOCKS / NXCD) + (bid >> 3);

    int tid = swz * BLOCK + threadIdx.x;
    int g = tid & 3;         // channel group: 4 floats each
    int p = tid >> 2;        // pixel index over B*H*W

    int x = p & (W - 1);
    int y = (p >> 9) & (H - 1);
    int b = p >> 18;

    // flow[...,0]=dy, flow[...,1]=dx ; query = grid - flow
    // 4 lanes of the same pixel read the same float2 (same cache line — free).
    float2 f = *reinterpret_cast<const float2*>(flow + (size_t)p * 2);
    float qy = (float)y - f.x;
    float qx = (float)x - f.y;

    float fy = fminf(fmaxf(floorf(qy), 0.0f), (float)(H - 2));
    float fx = fminf(fmaxf(floorf(qx), 0.0f), (float)(W - 2));
    float ay = fminf(fmaxf(qy - fy, 0.0f), 1.0f);
    float ax = fminf(fmaxf(qx - fx, 0.0f), 1.0f);
    int iy = (int)fy;
    int ix = (int)fx;

    const f4* base =
        reinterpret_cast<const f4*>(image + ((((size_t)b * H + iy) * W) + ix) * C);
    // row stride in f4 units: W*C/4 = 2048
    f4 tl = base[g];
    f4 tr = base[4 + g];
    f4 bl = base[(W * C / 4) + g];
    f4 br = base[(W * C / 4) + 4 + g];

    f4 top = lerp4(tl, tr, ax);
    f4 bot = lerp4(bl, br, ax);
    f4 res = lerp4(top, bot, ay);

    // Plain cached store this round (A/B vs round 4's non-temporal store):
    // testing whether the nt hint was capping write drain at ~1.4 TB/s.
    f4* o = reinterpret_cast<f4*>(out + (size_t)p * C) + g;
    *o = res;
}

extern "C" void kernel_launch(void* const* d_in, const int* in_sizes, int n_in,
                              void* d_out, int out_size, void* d_ws, size_t ws_size,
                              hipStream_t stream) {
    const float* image = (const float*)d_in[0];
    const float* flow  = (const float*)d_in[1];
    float* out = (float*)d_out;

    warp_bilinear_kernel<<<NBLOCKS, BLOCK, 0, stream>>>(image, flow, out);
}

// Round 8
// 233.938 us; speedup vs baseline: 1.1270x; 1.0726x over previous
//
#include <hip/hip_runtime.h>

// image: [8, 512, 512, 16] f32, flow: [8, 512, 512, 2] f32 -> out: [8, 512, 512, 16] f32
constexpr int B = 8;
constexpr int H = 512;
constexpr int W = 512;
constexpr int C = 16;

// 2-D tile blocks: 8 rows x 16 px per block, 4 lanes per pixel = 512 threads.
// Rationale: the gather footprint of one tile (~13 image rows x ~20 px x 64 B
// ~= 17 KB) fits in one CU's 32 KB L1, so the top/bottom row overlap between
// vertically-adjacent output rows is served by L1 instead of refetched from L2
// by a different CU (the failure mode of 1-row strip blocks).
constexpr int TROWS = 8;
constexpr int TCOLS = 16;
constexpr int BLOCK = TROWS * TCOLS * 4;            // 512 threads
constexpr int TILES_Y = H / TROWS;                  // 64
constexpr int TILES_X = W / TCOLS;                  // 32
constexpr int NBLOCKS = B * TILES_Y * TILES_X;      // 16384
// Vertical tile-neighbors: bid delta = TILES_X = 32, 32 % 8 XCDs == 0 -> same
// XCD under hardware round-robin. No explicit swizzle needed.

typedef float f4 __attribute__((ext_vector_type(4)));

__device__ __forceinline__ f4 lerp4(f4 a, f4 b, float t) {
    return a + t * (b - a);
}

__global__ __launch_bounds__(512) void warp_bilinear_kernel(
    const float* __restrict__ image,
    const float* __restrict__ flow,
    float* __restrict__ out) {

    int bid = blockIdx.x;
    int b  = bid >> 11;            // image index      (2048 tiles per image)
    int ty = (bid & 2047) >> 5;    // tile row  [0,64)
    int tx = bid & 31;             // tile col  [0,32)

    int t  = threadIdx.x;
    int g  = t & 3;                // channel group (4 floats)
    int xi = (t >> 2) & (TCOLS - 1);
    int r  = t >> 6;               // tile-local row — one wave64 = one row-segment
                                   // (16 px x 4 ch-lanes: stores stay 1 KB contiguous)

    int y = ty * TROWS + r;
    int x = tx * TCOLS + xi;
    int p = ((b << 9) + y << 9) + x;   // pixel index over B*H*W

    // flow[...,0]=dy, flow[...,1]=dx ; query = grid - flow
    float2 f = *reinterpret_cast<const float2*>(flow + (size_t)p * 2);
    float qy = (float)y - f.x;
    float qx = (float)x - f.y;

    float fy = fminf(fmaxf(floorf(qy), 0.0f), (float)(H - 2));
    float fx = fminf(fmaxf(floorf(qx), 0.0f), (float)(W - 2));
    float ay = fminf(fmaxf(qy - fy, 0.0f), 1.0f);
    float ax = fminf(fmaxf(qx - fx, 0.0f), 1.0f);
    int iy = (int)fy;
    int ix = (int)fx;

    const f4* base =
        reinterpret_cast<const f4*>(image + ((((size_t)b * H + iy) * W) + ix) * C);
    // row stride in f4 units: W*C/4 = 2048
    f4 tl = base[g];
    f4 tr = base[4 + g];
    f4 bl = base[(W * C / 4) + g];
    f4 br = base[(W * C / 4) + 4 + g];

    f4 top = lerp4(tl, tr, ax);
    f4 bot = lerp4(bl, br, ax);
    f4 res = lerp4(top, bot, ay);

    f4* o = reinterpret_cast<f4*>(out + (size_t)p * C) + g;
    *o = res;
}

extern "C" void kernel_launch(void* const* d_in, const int* in_sizes, int n_in,
                              void* d_out, int out_size, void* d_ws, size_t ws_size,
                              hipStream_t stream) {
    const float* image = (const float*)d_in[0];
    const float* flow  = (const float*)d_in[1];
    float* out = (float*)d_out;

    warp_bilinear_kernel<<<NBLOCKS, BLOCK, 0, stream>>>(image, flow, out);
}